// Round 10
// baseline (242.900 us; speedup 1.0000x reference)
//
#include <hip/hip_runtime.h>
#include <hip/hip_fp16.h>
#include <math.h>

#define T_LEN 8192
#define CHN 128
#define BATCH 16
#define NKCHUNK 16   // k-chunk = 512 = 8 tiles of 64

typedef short bf16x8 __attribute__((ext_vector_type(8)));
typedef float f32x16 __attribute__((ext_vector_type(16)));

#define SIN8 0.3826834323650898f
#define COS8 0.9238795325112868f
#define R22  0.70710678118654752f
#define SROW 72          // LDS row stride (ushorts) = 144 B, 16B-aligned
#define SPLANE (128 * SROW)

__device__ __forceinline__ ushort f2bf(float f) {
    unsigned u = __float_as_uint(f);
    unsigned r = (u + 0x7fffu + ((u >> 16) & 1u)) >> 16;
    return (ushort)r;
}

// Barrier that drains ONLY LDS ops (lgkmcnt), leaving global prefetch loads
// in flight (R8/R9: __syncthreads' vmcnt(0) drain was gram's serial stall).
__device__ __forceinline__ void barrier_lds_only() {
    asm volatile("s_waitcnt lgkmcnt(0)" ::: "memory");
    __builtin_amdgcn_s_barrier();
}

__device__ __forceinline__ float2 cadd(float2 a, float2 b) { return make_float2(a.x + b.x, a.y + b.y); }
__device__ __forceinline__ float2 csub(float2 a, float2 b) { return make_float2(a.x - b.x, a.y - b.y); }
__device__ __forceinline__ float2 cmul(float2 a, float2 b) {
    return make_float2(a.x * b.x - a.y * b.y, a.x * b.y + a.y * b.x);
}
// a * conj(b): inverse-direction twiddle apply from a forward twiddle set (free conj)
__device__ __forceinline__ float2 cmulc(float2 a, float2 b) {
    return make_float2(a.x * b.x + a.y * b.y, a.y * b.x - a.x * b.y);
}

struct W8 { float2 w1, w2, w4, w6; };

// forward twiddle set for revolution angle rev (rev = theta/2pi, negative for DIF)
__device__ __forceinline__ W8 mkw(float rev) {
    W8 w;
    float sn = __builtin_amdgcn_sinf(rev);   // v_sin_f32: input in revolutions, |rev|<1/8
    float cs = __builtin_amdgcn_cosf(rev);
    w.w1 = make_float2(cs, sn);
    w.w2 = make_float2(cs * cs - sn * sn, 2.f * cs * sn);
    w.w4 = cmul(w.w2, w.w2);
    w.w6 = cmul(w.w4, w.w2);
    return w;
}

__device__ __forceinline__ void r4f(float2 x0, float2 x1, float2 x2, float2 x3,
                                    float2 wa, float2 wb, float2 wc,
                                    float2& y0, float2& y1, float2& y2, float2& y3) {
    float2 t0 = cadd(x0, x2), t1 = csub(x0, x2);
    float2 t2 = cadd(x1, x3), t3 = csub(x1, x3);
    y0 = cadd(t0, t2);
    y1 = cmul(csub(t0, t2), wb);
    y2 = cmul(make_float2(t1.x + t3.y, t1.y - t3.x), wa);
    y3 = cmul(make_float2(t1.x - t3.y, t1.y + t3.x), wc);
}

// r4i with conj-applied twiddles (takes FWD set; conj is free inside cmulc)
__device__ __forceinline__ void r4i_c(float2 x0, float2 x1, float2 x2, float2 x3,
                                      float2 wa, float2 wb, float2 wc,
                                      float2& y0, float2& y1, float2& y2, float2& y3) {
    float2 a1 = cmulc(x1, wb);
    float2 a2 = cmulc(x2, wa);
    float2 a3 = cmulc(x3, wc);
    float2 u0 = cadd(x0, a1), u1 = csub(x0, a1);
    float2 p = cadd(a2, a3);
    float2 m = make_float2(-(a2.y - a3.y), a2.x - a3.x);
    y0 = cadd(u0, p); y2 = csub(u0, p);
    y1 = cadd(u1, m); y3 = csub(u1, m);
}

__device__ __forceinline__ void r8f_w(const float2* x, W8 w, float2* y) {
    float2 u0 = cadd(x[0], x[4]), u1 = cadd(x[1], x[5]), u2 = cadd(x[2], x[6]), u3 = cadd(x[3], x[7]);
    float2 e0 = cmul(csub(x[0], x[4]), w.w1);
    float2 e1 = cmul(csub(x[1], x[5]), w.w1);
    float2 e2 = cmul(csub(x[2], x[6]), w.w1);
    float2 e3 = cmul(csub(x[3], x[7]), w.w1);
    float2 v0 = e0;
    float2 v1 = make_float2(R22 * (e1.x + e1.y), R22 * (e1.y - e1.x));
    float2 v2 = make_float2(e2.y, -e2.x);
    float2 v3 = make_float2(R22 * (e3.y - e3.x), -R22 * (e3.x + e3.y));
    r4f(u0, u1, u2, u3, w.w2, w.w4, w.w6, y[0], y[1], y[2], y[3]);
    r4f(v0, v1, v2, v3, w.w2, w.w4, w.w6, y[4], y[5], y[6], y[7]);
}

// inverse radix-8 from a FORWARD twiddle set (conjugation folded into cmulc)
__device__ __forceinline__ void r8i_w(const float2* x, W8 w, float2* y) {
    float2 g0, g1, g2, g3, g4, g5, g6, g7;
    r4i_c(x[0], x[1], x[2], x[3], w.w2, w.w4, w.w6, g0, g1, g2, g3);
    r4i_c(x[4], x[5], x[6], x[7], w.w2, w.w4, w.w6, g4, g5, g6, g7);
    float2 t0 = cmulc(g4, w.w1);
    float2 e1 = cmulc(g5, w.w1);
    float2 e2 = cmulc(g6, w.w1);
    float2 e3 = cmulc(g7, w.w1);
    float2 t1 = make_float2(R22 * (e1.x - e1.y), R22 * (e1.x + e1.y));
    float2 t2 = make_float2(-e2.y, e2.x);
    float2 t3 = make_float2(-R22 * (e3.x + e3.y), R22 * (e3.x - e3.y));
    y[0] = cadd(g0, t0); y[4] = csub(g0, t0);
    y[1] = cadd(g1, t1); y[5] = csub(g1, t1);
    y[2] = cadd(g2, t2); y[6] = csub(g2, t2);
    y[3] = cadd(g3, t3); y[7] = csub(g3, t3);
}

// One block per (b,c) row. Same structure as R8/R9, plus: twiddle sets are
// computed ONCE per pass (j identical across the two s-iterations for
// Q=128/Q=16: 512 = 0 mod Q), cached in registers, and reused by the
// matching inverse pass via free conjugation. Middle twiddles are literals.
__global__ __launch_bounds__(512, 4) void fft_analytic_kernel(const float* __restrict__ x,
                                                              ushort* __restrict__ zc,
                                                              ushort* __restrict__ zs) {
    __shared__ __align__(16) float2 buf[T_LEN];   // 64 KiB
    const int tid = threadIdx.x;
    const int row = blockIdx.x;
    const float* xr = x + ((size_t)row << 13);

    // cached forward twiddle sets (must stay in registers: s-loops unrolled)
    W8 wL[2];
    const W8 w128 = mkw((float)(tid & 127) * (-1.f / 1024.f));
    const W8 w16  = mkw((float)(tid & 15)  * (-1.f / 128.f));

    // fwd pass Q=1024 fused with global load (x real; imag folds away)
#pragma unroll
    for (int s = 0; s < 2; ++s) {
        const int g = tid + (s << 9);
        float2 X[8], Y[8];
#pragma unroll
        for (int c = 0; c < 8; ++c) X[c] = make_float2(xr[g + (c << 10)], 0.f);
        wL[s] = mkw((float)g * (-1.f / 8192.f));
        r8f_w(X, wL[s], Y);
#pragma unroll
        for (int c = 0; c < 8; ++c) buf[g + (c << 10)] = Y[c];
    }
    __syncthreads();

    // fwd LDS pass Q=128
#pragma unroll
    for (int s = 0; s < 2; ++s) {
        const int g = tid + (s << 9);
        const int i = ((g & ~127) << 3) | (g & 127);
        float2 xx[8], yy[8];
#pragma unroll
        for (int c = 0; c < 8; ++c) xx[c] = buf[i + c * 128];
        r8f_w(xx, w128, yy);
#pragma unroll
        for (int c = 0; c < 8; ++c) buf[i + c * 128] = yy[c];
    }
    __syncthreads();

    // fwd LDS pass Q=16: plain reads, swizzled writes (slot = idx ^ 2c)
#pragma unroll
    for (int s = 0; s < 2; ++s) {
        const int g = tid + (s << 9);
        const int i = ((g & ~15) << 3) | (g & 15);
        float2 xx[8], yy[8];
#pragma unroll
        for (int c = 0; c < 8; ++c) xx[c] = buf[i + c * 16];
        r8f_w(xx, w16, yy);
#pragma unroll
        for (int c = 0; c < 8; ++c) buf[(i + c * 16) ^ (2 * c)] = yy[c];
    }
    __syncthreads();

    // register-local middle: thread owns elements [16*tid, 16*tid+16).
    // Element-float4 (8*tid+p) lives at slot4 (8*tid + (p^(tid&7))).
    {
        const W8 wID = { make_float2(1.f, 0.f), make_float2(1.f, 0.f),
                         make_float2(1.f, 0.f), make_float2(1.f, 0.f) };
        const W8 wO  = { make_float2(COS8, -SIN8), make_float2(R22, -R22),
                         make_float2(0.f, -1.f),   make_float2(-R22, -R22) };
        float2 v[16];
        float4* bb = (float4*)buf;
        const int K = tid & 7;
#pragma unroll
        for (int p = 0; p < 8; ++p) {
            float4 f = bb[8 * tid + (p ^ K)];
            v[2 * p]     = make_float2(f.x, f.y);
            v[2 * p + 1] = make_float2(f.z, f.w);
        }
        float2 xe[8], xo[8], E[8], O[8], t[8];
#pragma unroll
        for (int c = 0; c < 8; ++c) { xe[c] = v[2 * c]; xo[c] = v[2 * c + 1]; }
        r8f_w(xe, wID, E);
        r8f_w(xo, wO, O);
#pragma unroll
        for (int c = 0; c < 8; ++c) t[c] = cadd(E[c], O[c]);   // dist-1 + mask fuse
        r8i_w(t, wID, xe);
        r8i_w(t, wO, xo);
#pragma unroll
        for (int p = 0; p < 8; ++p)
            bb[8 * tid + (p ^ K)] = make_float4(xe[p].x, xe[p].y, xo[p].x, xo[p].y);
    }
    __syncthreads();

    // inv LDS pass Q=16: swizzled reads, plain writes (reuses w16)
#pragma unroll
    for (int s = 0; s < 2; ++s) {
        const int g = tid + (s << 9);
        const int i = ((g & ~15) << 3) | (g & 15);
        float2 xx[8], yy[8];
#pragma unroll
        for (int c = 0; c < 8; ++c) xx[c] = buf[(i + c * 16) ^ (2 * c)];
        r8i_w(xx, w16, yy);
#pragma unroll
        for (int c = 0; c < 8; ++c) buf[i + c * 16] = yy[c];
    }
    __syncthreads();

    // inv LDS pass Q=128 (reuses w128)
#pragma unroll
    for (int s = 0; s < 2; ++s) {
        const int g = tid + (s << 9);
        const int i = ((g & ~127) << 3) | (g & 127);
        float2 xx[8], yy[8];
#pragma unroll
        for (int c = 0; c < 8; ++c) xx[c] = buf[i + c * 128];
        r8i_w(xx, w128, yy);
#pragma unroll
        for (int c = 0; c < 8; ++c) buf[i + c * 128] = yy[c];
    }
    __syncthreads();

    // final inv pass Q=1024 (reuses wL[s]) fused with normalize + contiguous store
    ushort* zcr = zc + ((size_t)row << 13);
    ushort* zsr = zs + ((size_t)row << 13);
#pragma unroll
    for (int s = 0; s < 2; ++s) {
        const int g = tid + (s << 9);
        float2 xx[8], yy[8];
#pragma unroll
        for (int c = 0; c < 8; ++c) xx[c] = buf[g + (c << 10)];
        r8i_w(xx, wL[s], yy);
#pragma unroll
        for (int c = 0; c < 8; ++c) {
            float2 vv = yy[c];
            float n2 = vv.x * vv.x + vv.y * vv.y;
            float cc = 1.f, ss = 0.f;
            if (n2 > 0.f) { float inv = rsqrtf(n2); cc = vv.x * inv; ss = vv.y * inv; }
            zcr[g + (c << 10)] = f2bf(cc);
            zsr[g + (c << 10)] = f2bf(ss);
        }
    }
}

// MFMA Gram partials. grid=(BATCH, 2 col-halves, NKCHUNK) = 512 blocks of 512
// threads -> 2 blocks/CU so one block's barrier stalls hide under the other's
// compute. Block computes G[b][0:128][j0:j0+64] over its 512-k chunk.
// Depth-2 register prefetch + lgkm-only barriers (loads stay in flight).
__global__ __launch_bounds__(512, 2) void gram_kernel(const ushort* __restrict__ zc,
                                                      const ushort* __restrict__ zs,
                                                      __half2* __restrict__ partial) {
    const int b = blockIdx.x, jh = blockIdx.y, kc = blockIdx.z;
    const int j0 = jh * 64;
    const int tid = threadIdx.x;
    const int wave = tid >> 6;
    const int wr = wave & 3, wc2 = wave >> 2;
    const int lane31 = tid & 31;
    const int half = (tid >> 5) & 1;

    __shared__ __align__(16) ushort sZ[2 * SPLANE];

    f32x16 accRe, accIm;
#pragma unroll
    for (int r = 0; r < 16; ++r) { accRe[r] = 0.f; accIm[r] = 0.f; }

    const size_t base = ((size_t)b * CHN) << 13;
    const int k0 = kc << 9;   // *512

    const ushort* srcs[4];
    int ldst[4];
#pragma unroll
    for (int q = 0; q < 4; ++q) {
        int id = tid + (q << 9);                   // 0..2047 = plane*1024 + rid*8 + ck
        int plane = id >> 10;
        int rid = (id >> 3) & 127;
        int ck = id & 7;
        srcs[q] = (plane ? zs : zc) + base + ((size_t)rid << 13) + (size_t)(k0 + ck * 8);
        ldst[q] = plane * SPLANE + rid * SROW + ck * 8;
    }

    uint4 pre[2][4];
#pragma unroll
    for (int q = 0; q < 4; ++q) pre[0][q] = *(const uint4*)srcs[q];
#pragma unroll
    for (int q = 0; q < 4; ++q) pre[1][q] = *(const uint4*)(srcs[q] + 64);

#pragma unroll
    for (int it = 0; it < 8; ++it) {
        barrier_lds_only();                         // prev iter's ds_reads done
#pragma unroll
        for (int q = 0; q < 4; ++q) *(uint4*)&sZ[ldst[q]] = pre[it & 1][q];
        if (it < 6) {
#pragma unroll
            for (int q = 0; q < 4; ++q)
                pre[it & 1][q] = *(const uint4*)(srcs[q] + (it + 2) * 64);
        }
        barrier_lds_only();                         // ds_writes visible; vmem in flight
#pragma unroll
        for (int kb = 0; kb < 64; kb += 16) {
            const int aoff = (wr * 32 + lane31) * SROW + kb + half * 8;
            bf16x8 aC = *(const bf16x8*)&sZ[aoff];
            bf16x8 aS = *(const bf16x8*)&sZ[SPLANE + aoff];
            bf16x8 aCn;
#pragma unroll
            for (int r = 0; r < 8; ++r) aCn[r] = (short)(aC[r] ^ (short)0x8000);
            const int boff = (j0 + wc2 * 32 + lane31) * SROW + kb + half * 8;
            bf16x8 bC = *(const bf16x8*)&sZ[boff];
            bf16x8 bS = *(const bf16x8*)&sZ[SPLANE + boff];
            accRe = __builtin_amdgcn_mfma_f32_32x32x16_bf16(aC,  bC, accRe, 0, 0, 0);
            accIm = __builtin_amdgcn_mfma_f32_32x32x16_bf16(aS,  bC, accIm, 0, 0, 0);
            accRe = __builtin_amdgcn_mfma_f32_32x32x16_bf16(aS,  bS, accRe, 0, 0, 0);
            accIm = __builtin_amdgcn_mfma_f32_32x32x16_bf16(aCn, bS, accIm, 0, 0, 0);
        }
    }

    // C/D layout (verified m74/m101): col=lane&31, row=(reg&3)+8*(reg>>2)+4*(lane>>5)
    __half2* pb = partial + ((size_t)(kc * BATCH + b) << 14);
#pragma unroll
    for (int r = 0; r < 16; ++r) {
        int rrow = (r & 3) + 8 * (r >> 2) + 4 * half;
        int i = wr * 32 + rrow;
        int j = j0 + wc2 * 32 + lane31;
        pb[i * CHN + j] = __floats2half2_rn(accRe[r], accIm[r]);
    }
}

__global__ __launch_bounds__(256) void reduce_kernel(const __half2* __restrict__ partial,
                                                     float* __restrict__ out) {
    const size_t i = (size_t)blockIdx.x * 256 + threadIdx.x;
    const size_t n = (size_t)BATCH * CHN * CHN;
    if (i >= n) return;
    float re = 0.0f, im = 0.0f;
#pragma unroll
    for (int c = 0; c < NKCHUNK; ++c) {
        float2 p = __half22float2(partial[(size_t)c * n + i]);
        re += p.x;
        im += p.y;
    }
    out[i] = sqrtf(re * re + im * im) * (1.0f / (float)T_LEN);
}

extern "C" void kernel_launch(void* const* d_in, const int* in_sizes, int n_in,
                              void* d_out, int out_size, void* d_ws, size_t ws_size,
                              hipStream_t stream) {
    const float* x = (const float*)d_in[0];
    float* out = (float*)d_out;

    const size_t plane_elems = (size_t)BATCH * CHN * T_LEN;                 // 16.8M
    ushort* zc = (ushort*)d_ws;                                             // 33.55 MB
    ushort* zs = zc + plane_elems;                                          // +33.55 MB
    __half2* partial = (__half2*)((char*)d_ws + 2 * plane_elems * sizeof(ushort)); // +16.78 MB

    fft_analytic_kernel<<<BATCH * CHN, 512, 0, stream>>>(x, zc, zs);

    dim3 g2(BATCH, 2, NKCHUNK);
    gram_kernel<<<g2, 512, 0, stream>>>(zc, zs, partial);

    const int n_out = BATCH * CHN * CHN;
    reduce_kernel<<<(n_out + 255) / 256, 256, 0, stream>>>(partial, out);
}

// Round 11
// 233.991 us; speedup vs baseline: 1.0381x; 1.0381x over previous
//
#include <hip/hip_runtime.h>
#include <hip/hip_fp16.h>
#include <math.h>

#define T_LEN 8192
#define CHN 128
#define BATCH 16
#define NKCHUNK 16   // k-chunk = 512 = 8 tiles of 64

typedef short bf16x8 __attribute__((ext_vector_type(8)));
typedef float f32x16 __attribute__((ext_vector_type(16)));

#define SIN8 0.3826834323650898f
#define COS8 0.9238795325112868f
#define R22  0.70710678118654752f
#define SROW 72          // LDS row stride (ushorts) = 144 B, 16B-aligned
#define SPLANE (128 * SROW)

__device__ __forceinline__ ushort f2bf(float f) {
    unsigned u = __float_as_uint(f);
    unsigned r = (u + 0x7fffu + ((u >> 16) & 1u)) >> 16;
    return (ushort)r;
}

// Barrier that drains ONLY LDS ops (lgkmcnt), leaving global prefetch loads
// in flight (R8/R9: __syncthreads' vmcnt(0) drain was gram's serial stall).
__device__ __forceinline__ void barrier_lds_only() {
    asm volatile("s_waitcnt lgkmcnt(0)" ::: "memory");
    __builtin_amdgcn_s_barrier();
}

__device__ __forceinline__ float2 cadd(float2 a, float2 b) { return make_float2(a.x + b.x, a.y + b.y); }
__device__ __forceinline__ float2 csub(float2 a, float2 b) { return make_float2(a.x - b.x, a.y - b.y); }
__device__ __forceinline__ float2 cmul(float2 a, float2 b) {
    return make_float2(a.x * b.x - a.y * b.y, a.x * b.y + a.y * b.x);
}
// a * conj(b): inverse twiddle apply from a forward twiddle set (free conj)
__device__ __forceinline__ float2 cmulc(float2 a, float2 b) {
    return make_float2(a.x * b.x + a.y * b.y, a.y * b.x - a.x * b.y);
}

struct W8 { float2 w1, w2, w4, w6; };

// FORWARD twiddle set for revolution angle rev (= theta/2pi, negative for DIF).
// v_sin/v_cos take revolutions; all our |rev| <= 0.125 so no range reduction
// needed (validated on HW in R10: absmax unchanged).
__device__ __forceinline__ W8 mkw(float rev) {
    W8 w;
    float sn = __builtin_amdgcn_sinf(rev);
    float cs = __builtin_amdgcn_cosf(rev);
    w.w1 = make_float2(cs, sn);
    w.w2 = make_float2(cs * cs - sn * sn, 2.f * cs * sn);
    w.w4 = cmul(w.w2, w.w2);
    w.w6 = cmul(w.w4, w.w2);
    return w;
}

__device__ __forceinline__ void r4f(float2 x0, float2 x1, float2 x2, float2 x3,
                                    float2 wa, float2 wb, float2 wc,
                                    float2& y0, float2& y1, float2& y2, float2& y3) {
    float2 t0 = cadd(x0, x2), t1 = csub(x0, x2);
    float2 t2 = cadd(x1, x3), t3 = csub(x1, x3);
    y0 = cadd(t0, t2);
    y1 = cmul(csub(t0, t2), wb);
    y2 = cmul(make_float2(t1.x + t3.y, t1.y - t3.x), wa);
    y3 = cmul(make_float2(t1.x - t3.y, t1.y + t3.x), wc);
}

// r4i with conj-applied twiddles (takes FWD set; conj folded into cmulc)
__device__ __forceinline__ void r4i_c(float2 x0, float2 x1, float2 x2, float2 x3,
                                      float2 wa, float2 wb, float2 wc,
                                      float2& y0, float2& y1, float2& y2, float2& y3) {
    float2 a1 = cmulc(x1, wb);
    float2 a2 = cmulc(x2, wa);
    float2 a3 = cmulc(x3, wc);
    float2 u0 = cadd(x0, a1), u1 = csub(x0, a1);
    float2 p = cadd(a2, a3);
    float2 m = make_float2(-(a2.y - a3.y), a2.x - a3.x);
    y0 = cadd(u0, p); y2 = csub(u0, p);
    y1 = cadd(u1, m); y3 = csub(u1, m);
}

__device__ __forceinline__ void r8f_w(const float2* x, W8 w, float2* y) {
    float2 u0 = cadd(x[0], x[4]), u1 = cadd(x[1], x[5]), u2 = cadd(x[2], x[6]), u3 = cadd(x[3], x[7]);
    float2 e0 = cmul(csub(x[0], x[4]), w.w1);
    float2 e1 = cmul(csub(x[1], x[5]), w.w1);
    float2 e2 = cmul(csub(x[2], x[6]), w.w1);
    float2 e3 = cmul(csub(x[3], x[7]), w.w1);
    float2 v0 = e0;
    float2 v1 = make_float2(R22 * (e1.x + e1.y), R22 * (e1.y - e1.x));
    float2 v2 = make_float2(e2.y, -e2.x);
    float2 v3 = make_float2(R22 * (e3.x * 0.f + e3.y - e3.x), -R22 * (e3.x + e3.y));
    // NOTE: v3 simplification kept literal-identical to verified form below:
    v3 = make_float2(R22 * (e3.y - e3.x), -R22 * (e3.x + e3.y));
    r4f(u0, u1, u2, u3, w.w2, w.w4, w.w6, y[0], y[1], y[2], y[3]);
    r4f(v0, v1, v2, v3, w.w2, w.w4, w.w6, y[4], y[5], y[6], y[7]);
}

// inverse radix-8 from a FORWARD twiddle set (conjugation folded into cmulc)
__device__ __forceinline__ void r8i_w(const float2* x, W8 w, float2* y) {
    float2 g0, g1, g2, g3, g4, g5, g6, g7;
    r4i_c(x[0], x[1], x[2], x[3], w.w2, w.w4, w.w6, g0, g1, g2, g3);
    r4i_c(x[4], x[5], x[6], x[7], w.w2, w.w4, w.w6, g4, g5, g6, g7);
    float2 t0 = cmulc(g4, w.w1);
    float2 e1 = cmulc(g5, w.w1);
    float2 e2 = cmulc(g6, w.w1);
    float2 e3 = cmulc(g7, w.w1);
    float2 t1 = make_float2(R22 * (e1.x - e1.y), R22 * (e1.x + e1.y));
    float2 t2 = make_float2(-e2.y, e2.x);
    float2 t3 = make_float2(-R22 * (e3.x + e3.y), R22 * (e3.x - e3.y));
    y[0] = cadd(g0, t0); y[4] = csub(g0, t0);
    y[1] = cadd(g1, t1); y[5] = csub(g1, t1);
    y[2] = cadd(g2, t2); y[6] = csub(g2, t2);
    y[3] = cadd(g3, t3); y[7] = csub(g3, t3);
}

// One block per (b,c) row. R9-known-good structure. Twiddles: raw v_sin/v_cos,
// computed once per pass with PASS-LOCAL live range only — cross-pass caching
// spills to scratch (R10: +400 MB HBM, fft 77->133 us). No state survives a
// __syncthreads except the loop-invariant row pointer.
__global__ __launch_bounds__(512, 4) void fft_analytic_kernel(const float* __restrict__ x,
                                                              ushort* __restrict__ zc,
                                                              ushort* __restrict__ zs) {
    __shared__ __align__(16) float2 buf[T_LEN];   // 64 KiB
    const int tid = threadIdx.x;
    const int row = blockIdx.x;
    const float* xr = x + ((size_t)row << 13);

    // fwd pass Q=1024 fused with global load (x real; imag folds away)
#pragma unroll
    for (int s = 0; s < 2; ++s) {
        const int g = tid + (s << 9);
        float2 X[8], Y[8];
#pragma unroll
        for (int c = 0; c < 8; ++c) X[c] = make_float2(xr[g + (c << 10)], 0.f);
        W8 w = mkw((float)g * (-1.f / 8192.f));
        r8f_w(X, w, Y);
#pragma unroll
        for (int c = 0; c < 8; ++c) buf[g + (c << 10)] = Y[c];
    }
    __syncthreads();

    // fwd LDS pass Q=128 (j = tid&127 identical for both s: one twiddle set)
    {
        W8 w = mkw((float)(tid & 127) * (-1.f / 1024.f));
#pragma unroll
        for (int s = 0; s < 2; ++s) {
            const int g = tid + (s << 9);
            const int i = ((g & ~127) << 3) | (g & 127);
            float2 xx[8], yy[8];
#pragma unroll
            for (int c = 0; c < 8; ++c) xx[c] = buf[i + c * 128];
            r8f_w(xx, w, yy);
#pragma unroll
            for (int c = 0; c < 8; ++c) buf[i + c * 128] = yy[c];
        }
    }
    __syncthreads();

    // fwd LDS pass Q=16: plain reads, swizzled writes (slot = idx ^ 2c)
    {
        W8 w = mkw((float)(tid & 15) * (-1.f / 128.f));
#pragma unroll
        for (int s = 0; s < 2; ++s) {
            const int g = tid + (s << 9);
            const int i = ((g & ~15) << 3) | (g & 15);
            float2 xx[8], yy[8];
#pragma unroll
            for (int c = 0; c < 8; ++c) xx[c] = buf[i + c * 16];
            r8f_w(xx, w, yy);
#pragma unroll
            for (int c = 0; c < 8; ++c) buf[(i + c * 16) ^ (2 * c)] = yy[c];
        }
    }
    __syncthreads();

    // register-local middle: thread owns elements [16*tid, 16*tid+16).
    // Element-float4 (8*tid+p) lives at slot4 (8*tid + (p^(tid&7))).
    // All indices compile-time (scratch tripwire), twiddles literal.
    {
        const W8 wID = { make_float2(1.f, 0.f), make_float2(1.f, 0.f),
                         make_float2(1.f, 0.f), make_float2(1.f, 0.f) };
        const W8 wO  = { make_float2(COS8, -SIN8), make_float2(R22, -R22),
                         make_float2(0.f, -1.f),   make_float2(-R22, -R22) };
        float2 v[16];
        float4* bb = (float4*)buf;
        const int K = tid & 7;
#pragma unroll
        for (int p = 0; p < 8; ++p) {
            float4 f = bb[8 * tid + (p ^ K)];
            v[2 * p]     = make_float2(f.x, f.y);
            v[2 * p + 1] = make_float2(f.z, f.w);
        }
        float2 xe[8], xo[8], E[8], O[8], t[8];
#pragma unroll
        for (int c = 0; c < 8; ++c) { xe[c] = v[2 * c]; xo[c] = v[2 * c + 1]; }
        r8f_w(xe, wID, E);
        r8f_w(xo, wO, O);
#pragma unroll
        for (int c = 0; c < 8; ++c) t[c] = cadd(E[c], O[c]);   // dist-1 + mask fuse
        r8i_w(t, wID, xe);
        r8i_w(t, wO, xo);
#pragma unroll
        for (int p = 0; p < 8; ++p)
            bb[8 * tid + (p ^ K)] = make_float4(xe[p].x, xe[p].y, xo[p].x, xo[p].y);
    }
    __syncthreads();

    // inv LDS pass Q=16: swizzled reads, plain writes
    {
        W8 w = mkw((float)(tid & 15) * (-1.f / 128.f));
#pragma unroll
        for (int s = 0; s < 2; ++s) {
            const int g = tid + (s << 9);
            const int i = ((g & ~15) << 3) | (g & 15);
            float2 xx[8], yy[8];
#pragma unroll
            for (int c = 0; c < 8; ++c) xx[c] = buf[(i + c * 16) ^ (2 * c)];
            r8i_w(xx, w, yy);
#pragma unroll
            for (int c = 0; c < 8; ++c) buf[i + c * 16] = yy[c];
        }
    }
    __syncthreads();

    // inv LDS pass Q=128
    {
        W8 w = mkw((float)(tid & 127) * (-1.f / 1024.f));
#pragma unroll
        for (int s = 0; s < 2; ++s) {
            const int g = tid + (s << 9);
            const int i = ((g & ~127) << 3) | (g & 127);
            float2 xx[8], yy[8];
#pragma unroll
            for (int c = 0; c < 8; ++c) xx[c] = buf[i + c * 128];
            r8i_w(xx, w, yy);
#pragma unroll
            for (int c = 0; c < 8; ++c) buf[i + c * 128] = yy[c];
        }
    }
    __syncthreads();

    // final inv pass Q=1024 fused with normalize + contiguous row-major store
    ushort* zcr = zc + ((size_t)row << 13);
    ushort* zsr = zs + ((size_t)row << 13);
#pragma unroll
    for (int s = 0; s < 2; ++s) {
        const int g = tid + (s << 9);
        float2 xx[8], yy[8];
#pragma unroll
        for (int c = 0; c < 8; ++c) xx[c] = buf[g + (c << 10)];
        W8 w = mkw((float)g * (-1.f / 8192.f));
        r8i_w(xx, w, yy);
#pragma unroll
        for (int c = 0; c < 8; ++c) {
            float2 vv = yy[c];
            float n2 = vv.x * vv.x + vv.y * vv.y;
            float cc = 1.f, ss = 0.f;
            if (n2 > 0.f) { float inv = rsqrtf(n2); cc = vv.x * inv; ss = vv.y * inv; }
            zcr[g + (c << 10)] = f2bf(cc);
            zsr[g + (c << 10)] = f2bf(ss);
        }
    }
}

// MFMA Gram partials — R9-known-good config. grid=(BATCH, NKCHUNK), block=512
// (8 waves). Wave (wr=w&3, wcol=w>>2): rows wr*32..+32, cols wcol*64..+64.
// Depth-2 register prefetch + lgkm-only barriers (loads stay in flight).
__global__ __launch_bounds__(512, 2) void gram_kernel(const ushort* __restrict__ zc,
                                                      const ushort* __restrict__ zs,
                                                      __half2* __restrict__ partial) {
    const int b = blockIdx.x, kc = blockIdx.y;
    const int tid = threadIdx.x;
    const int wave = tid >> 6;
    const int wr = wave & 3, wcol = wave >> 2;
    const int lane31 = tid & 31;
    const int half = (tid >> 5) & 1;

    __shared__ __align__(16) ushort sZ[2 * SPLANE];

    f32x16 accRe[2], accIm[2];
#pragma unroll
    for (int v = 0; v < 2; ++v)
#pragma unroll
        for (int r = 0; r < 16; ++r) { accRe[v][r] = 0.f; accIm[v][r] = 0.f; }

    const size_t base = ((size_t)b * CHN) << 13;
    const int k0 = kc << 9;   // *512

    const ushort* srcs[4];
    int ldst[4];
#pragma unroll
    for (int q = 0; q < 4; ++q) {
        int id = tid + (q << 9);                   // 0..2047 = plane*1024 + rid*8 + ck
        int plane = id >> 10;
        int rid = (id >> 3) & 127;
        int ck = id & 7;
        srcs[q] = (plane ? zs : zc) + base + ((size_t)rid << 13) + (size_t)(k0 + ck * 8);
        ldst[q] = plane * SPLANE + rid * SROW + ck * 8;
    }

    uint4 pre[2][4];
#pragma unroll
    for (int q = 0; q < 4; ++q) pre[0][q] = *(const uint4*)srcs[q];
#pragma unroll
    for (int q = 0; q < 4; ++q) pre[1][q] = *(const uint4*)(srcs[q] + 64);

#pragma unroll
    for (int it = 0; it < 8; ++it) {
        barrier_lds_only();                         // prev iter's ds_reads done
#pragma unroll
        for (int q = 0; q < 4; ++q) *(uint4*)&sZ[ldst[q]] = pre[it & 1][q];
        if (it < 6) {
#pragma unroll
            for (int q = 0; q < 4; ++q)
                pre[it & 1][q] = *(const uint4*)(srcs[q] + (it + 2) * 64);
        }
        barrier_lds_only();                         // ds_writes visible; vmem in flight
#pragma unroll
        for (int kb = 0; kb < 64; kb += 16) {
            const int aoff = (wr * 32 + lane31) * SROW + kb + half * 8;
            bf16x8 aC = *(const bf16x8*)&sZ[aoff];
            bf16x8 aS = *(const bf16x8*)&sZ[SPLANE + aoff];
            bf16x8 aCn;
#pragma unroll
            for (int r = 0; r < 8; ++r) aCn[r] = (short)(aC[r] ^ (short)0x8000);
            bf16x8 bC[2], bS[2];
#pragma unroll
            for (int v = 0; v < 2; ++v) {
                const int boff = (wcol * 64 + v * 32 + lane31) * SROW + kb + half * 8;
                bC[v] = *(const bf16x8*)&sZ[boff];
                bS[v] = *(const bf16x8*)&sZ[SPLANE + boff];
            }
            accRe[0] = __builtin_amdgcn_mfma_f32_32x32x16_bf16(aC,  bC[0], accRe[0], 0, 0, 0);
            accRe[1] = __builtin_amdgcn_mfma_f32_32x32x16_bf16(aC,  bC[1], accRe[1], 0, 0, 0);
            accIm[0] = __builtin_amdgcn_mfma_f32_32x32x16_bf16(aS,  bC[0], accIm[0], 0, 0, 0);
            accIm[1] = __builtin_amdgcn_mfma_f32_32x32x16_bf16(aS,  bC[1], accIm[1], 0, 0, 0);
            accRe[0] = __builtin_amdgcn_mfma_f32_32x32x16_bf16(aS,  bS[0], accRe[0], 0, 0, 0);
            accRe[1] = __builtin_amdgcn_mfma_f32_32x32x16_bf16(aS,  bS[1], accRe[1], 0, 0, 0);
            accIm[0] = __builtin_amdgcn_mfma_f32_32x32x16_bf16(aCn, bS[0], accIm[0], 0, 0, 0);
            accIm[1] = __builtin_amdgcn_mfma_f32_32x32x16_bf16(aCn, bS[1], accIm[1], 0, 0, 0);
        }
    }

    // C/D layout (verified m74/m101): col=lane&31, row=(reg&3)+8*(reg>>2)+4*(lane>>5)
    __half2* pb = partial + ((size_t)(kc * BATCH + b) << 14);
#pragma unroll
    for (int v = 0; v < 2; ++v)
#pragma unroll
        for (int r = 0; r < 16; ++r) {
            int rrow = (r & 3) + 8 * (r >> 2) + 4 * half;
            int i = wr * 32 + rrow;
            int j = wcol * 64 + v * 32 + lane31;
            pb[i * CHN + j] = __floats2half2_rn(accRe[v][r], accIm[v][r]);
        }
}

__global__ __launch_bounds__(256) void reduce_kernel(const __half2* __restrict__ partial,
                                                     float* __restrict__ out) {
    const size_t i = (size_t)blockIdx.x * 256 + threadIdx.x;
    const size_t n = (size_t)BATCH * CHN * CHN;
    if (i >= n) return;
    float re = 0.0f, im = 0.0f;
#pragma unroll
    for (int c = 0; c < NKCHUNK; ++c) {
        float2 p = __half22float2(partial[(size_t)c * n + i]);
        re += p.x;
        im += p.y;
    }
    out[i] = sqrtf(re * re + im * im) * (1.0f / (float)T_LEN);
}

extern "C" void kernel_launch(void* const* d_in, const int* in_sizes, int n_in,
                              void* d_out, int out_size, void* d_ws, size_t ws_size,
                              hipStream_t stream) {
    const float* x = (const float*)d_in[0];
    float* out = (float*)d_out;

    const size_t plane_elems = (size_t)BATCH * CHN * T_LEN;                 // 16.8M
    ushort* zc = (ushort*)d_ws;                                             // 33.55 MB
    ushort* zs = zc + plane_elems;                                          // +33.55 MB
    __half2* partial = (__half2*)((char*)d_ws + 2 * plane_elems * sizeof(ushort)); // +16.78 MB

    fft_analytic_kernel<<<BATCH * CHN, 512, 0, stream>>>(x, zc, zs);

    dim3 g2(BATCH, NKCHUNK);
    gram_kernel<<<g2, 512, 0, stream>>>(zc, zs, partial);

    const int n_out = BATCH * CHN * CHN;
    reduce_kernel<<<(n_out + 255) / 256, 256, 0, stream>>>(partial, out);
}